// Round 10
// baseline (217.176 us; speedup 1.0000x reference)
//
#include <hip/hip_runtime.h>
#include <math.h>

// x [B=16, Cin=16, N=512, T=64], D=8, heads H=4, head_dim K=2
#define NPOS      524288   // B*T*N
#define CH_STRIDE 32768    // N*T
#define B_STRIDE  524288   // Cin*N*T
#define BN_EPS    1e-5f
#define INV_NPOS  (1.0f / 524288.0f)
#define LOG2E     1.44269504088896340736f

__device__ __forceinline__ float wave_red64(float v) {
    v += __shfl_xor(v, 32);
    v += __shfl_xor(v, 16);
    v += __shfl_xor(v, 8);
    v += __shfl_xor(v, 4);
    v += __shfl_xor(v, 2);
    v += __shfl_xor(v, 1);
    return v;
}

__device__ __forceinline__ float exp2_fast(float x) {
#if __has_builtin(__builtin_amdgcn_exp2f)
    return __builtin_amdgcn_exp2f(x);
#else
    float r;
    asm volatile("v_exp_f32 %0, %1\n\ts_nop 1" : "=v"(r) : "v"(x));
    return r;
#endif
}

__device__ __forceinline__ float rlane(float v, int lane) {
    return __int_as_float(__builtin_amdgcn_readlane(__float_as_int(v), lane));
}

// ---------------- Kernel A: per-channel sum/sumsq of y = x@W + b for q,k,v ----------------
// 512 blocks x 256 thr; each thread: 4 consecutive positions via float4 loads. (R3-proven)
__global__ __launch_bounds__(256) void stats_qkv_kernel(
    const float* __restrict__ x,
    const float* __restrict__ Wq, const float* __restrict__ bq,
    const float* __restrict__ Wk, const float* __restrict__ bk,
    const float* __restrict__ Wv, const float* __restrict__ bv,
    float* __restrict__ stats /* [48]: sum[24], sumsq[24] */)
{
    float acc_s[24], acc_q[24];
#pragma unroll
    for (int j = 0; j < 24; ++j) { acc_s[j] = 0.f; acc_q[j] = 0.f; }

    int t = blockIdx.x * 256 + threadIdx.x;   // 131072 threads
    int p = t * 4;
    int b = p >> 15;
    int r = p & 32767;
    const float* xb = x + b * B_STRIDE + r;

    float4 xv[16];
#pragma unroll
    for (int c = 0; c < 16; ++c) xv[c] = *(const float4*)(xb + c * CH_STRIDE);

#pragma unroll
    for (int j = 0; j < 8; ++j) {
        float4 yq = make_float4(bq[j], bq[j], bq[j], bq[j]);
        float4 yk = make_float4(bk[j], bk[j], bk[j], bk[j]);
        float4 yv = make_float4(bv[j], bv[j], bv[j], bv[j]);
#pragma unroll
        for (int c = 0; c < 16; ++c) {
            float wq = Wq[c * 8 + j], wk = Wk[c * 8 + j], wv = Wv[c * 8 + j];
            yq.x = fmaf(xv[c].x, wq, yq.x); yq.y = fmaf(xv[c].y, wq, yq.y);
            yq.z = fmaf(xv[c].z, wq, yq.z); yq.w = fmaf(xv[c].w, wq, yq.w);
            yk.x = fmaf(xv[c].x, wk, yk.x); yk.y = fmaf(xv[c].y, wk, yk.y);
            yk.z = fmaf(xv[c].z, wk, yk.z); yk.w = fmaf(xv[c].w, wk, yk.w);
            yv.x = fmaf(xv[c].x, wv, yv.x); yv.y = fmaf(xv[c].y, wv, yv.y);
            yv.z = fmaf(xv[c].z, wv, yv.z); yv.w = fmaf(xv[c].w, wv, yv.w);
        }
        acc_s[j]      += (yq.x + yq.y) + (yq.z + yq.w);
        acc_q[j]      += fmaf(yq.x, yq.x, yq.y * yq.y) + fmaf(yq.z, yq.z, yq.w * yq.w);
        acc_s[8 + j]  += (yk.x + yk.y) + (yk.z + yk.w);
        acc_q[8 + j]  += fmaf(yk.x, yk.x, yk.y * yk.y) + fmaf(yk.z, yk.z, yk.w * yk.w);
        acc_s[16 + j] += (yv.x + yv.y) + (yv.z + yv.w);
        acc_q[16 + j] += fmaf(yv.x, yv.x, yv.y * yv.y) + fmaf(yv.z, yv.z, yv.w * yv.w);
    }

    __shared__ float red[4][48];
    int w = threadIdx.x >> 6, lane = threadIdx.x & 63;
#pragma unroll
    for (int j = 0; j < 24; ++j) {
        float vs = wave_red64(acc_s[j]);
        float vq = wave_red64(acc_q[j]);
        if (lane == 0) { red[w][j] = vs; red[w][24 + j] = vq; }
    }
    __syncthreads();
    if (threadIdx.x < 48) {
        float v = red[0][threadIdx.x] + red[1][threadIdx.x] + red[2][threadIdx.x] + red[3][threadIdx.x];
        atomicAdd(&stats[threadIdx.x], v);
    }
}

// ---------------- Kernel B: fused BN-fold + qkv + attention + statsA epilogue ----------------
// One wave per (b,n) pair. lane = t. k/v broadcast via v_readlane (VALU pipe — measured
// faster than LDS broadcast: 62.7 vs 82 us; DS pipe is 1/CU, VALU is 4 SIMDs/CU).
__global__ __launch_bounds__(256) void attn_kernel(
    const float* __restrict__ x, const float* __restrict__ stats,
    const float* __restrict__ Wq, const float* __restrict__ bq,
    const float* __restrict__ gq, const float* __restrict__ betaq,
    const float* __restrict__ Wk, const float* __restrict__ bk,
    const float* __restrict__ gk, const float* __restrict__ betak,
    const float* __restrict__ Wv, const float* __restrict__ bv,
    const float* __restrict__ gv, const float* __restrict__ betav,
    float* __restrict__ attnbuf /* [8192][64][8] */,
    float* __restrict__ statsA  /* [44]: sum[8], cross[36] */)
{
    __shared__ float effW[24][16];       // [out j][in c]
    __shared__ float effB[24];
    __shared__ float sA[44];

    int tid = threadIdx.x;
    if (tid < 24) {
        int grp = tid >> 3, jj = tid & 7;
        const float* W  = (grp == 0) ? Wq : (grp == 1) ? Wk : Wv;
        const float* bb = (grp == 0) ? bq : (grp == 1) ? bk : bv;
        const float* g  = (grp == 0) ? gq : (grp == 1) ? gk : gv;
        const float* be = (grp == 0) ? betaq : (grp == 1) ? betak : betav;
        float mean = stats[tid] * INV_NPOS;
        float var  = stats[24 + tid] * INV_NPOS - mean * mean;
        float s    = g[jj] * rsqrtf(var + BN_EPS);
        float a    = (grp == 0) ? 0.5f * LOG2E : 1.0f;  // fold 1/sqrt(d) + log2e into q (relu(y)*a==relu(y*a), a>0)
        float sa   = s * a;
        for (int c = 0; c < 16; ++c) effW[tid][c] = W[c * 8 + jj] * sa;
        effB[tid] = (bb[jj] * s + be[jj] - mean * s) * a;
    }
    if (tid < 44) sA[tid] = 0.f;
    __syncthreads();

    int w = tid >> 6, lane = tid & 63;
    int pair = blockIdx.x * 4 + w;     // grid 2048 -> 8192 pairs
    int b = pair >> 9, n = pair & 511;
    const float* xb = x + b * B_STRIDE + n * 64 + lane;

    float xv[16];
#pragma unroll
    for (int c = 0; c < 16; ++c) xv[c] = xb[c * CH_STRIDE];

    float q[8], kk[8], vv[8];
#pragma unroll
    for (int jj = 0; jj < 8; ++jj) {
        float yq = effB[jj], yk = effB[8 + jj], yv = effB[16 + jj];
        const float4* wq4 = (const float4*)(&effW[jj][0]);
        const float4* wk4 = (const float4*)(&effW[8 + jj][0]);
        const float4* wv4 = (const float4*)(&effW[16 + jj][0]);
#pragma unroll
        for (int c4 = 0; c4 < 4; ++c4) {
            float4 a4 = wq4[c4], b4 = wk4[c4], c4v = wv4[c4];
            yq = fmaf(xv[4*c4+0], a4.x, fmaf(xv[4*c4+1], a4.y, fmaf(xv[4*c4+2], a4.z, fmaf(xv[4*c4+3], a4.w, yq))));
            yk = fmaf(xv[4*c4+0], b4.x, fmaf(xv[4*c4+1], b4.y, fmaf(xv[4*c4+2], b4.z, fmaf(xv[4*c4+3], b4.w, yk))));
            yv = fmaf(xv[4*c4+0], c4v.x, fmaf(xv[4*c4+1], c4v.y, fmaf(xv[4*c4+2], c4v.z, fmaf(xv[4*c4+3], c4v.w, yv))));
        }
        q[jj]  = fmaxf(yq, 0.f);
        kk[jj] = fmaxf(yk, 0.f);
        vv[jj] = fmaxf(yv, 0.f);
    }

    float se[4], o0[4], o1[4];
#pragma unroll
    for (int h = 0; h < 4; ++h) { se[h] = 0.f; o0[h] = 0.f; o1[h] = 0.f; }

#pragma unroll 8
    for (int j = 0; j < 64; ++j) {
#pragma unroll
        for (int h = 0; h < 4; ++h) {
            float k0 = rlane(kk[2*h],     j);
            float k1 = rlane(kk[2*h + 1], j);
            float v0 = rlane(vv[2*h],     j);
            float v1 = rlane(vv[2*h + 1], j);
            float e = exp2_fast(fmaf(q[2*h], k0, q[2*h + 1] * k1));
            se[h] += e;
            o0[h] = fmaf(e, v0, o0[h]);
            o1[h] = fmaf(e, v1, o1[h]);
        }
    }

    float out[8];
#pragma unroll
    for (int h = 0; h < 4; ++h) {
        float inv = 1.0f / se[h];
        out[2*h]     = o0[h] * inv;
        out[2*h + 1] = o1[h] * inv;
    }

    float4* dst = (float4*)(attnbuf + (size_t)pair * 512 + lane * 8);
    dst[0] = make_float4(out[0], out[1], out[2], out[3]);
    dst[1] = make_float4(out[4], out[5], out[6], out[7]);

    // statsA epilogue (post-loop, no inner-loop liveness)
#pragma unroll
    for (int i = 0; i < 8; ++i) {
        float t = wave_red64(out[i]);
        if (lane == 0) atomicAdd(&sA[i], t);
    }
    {
        int cnt = 8;
#pragma unroll
        for (int i = 0; i < 8; ++i) {
#pragma unroll
            for (int j2 = i; j2 < 8; ++j2) {
                float t = wave_red64(out[i] * out[j2]);
                if (lane == 0) atomicAdd(&sA[cnt], t);
                ++cnt;
            }
        }
    }
    __syncthreads();
    if (tid < 44) atomicAdd(&statsA[tid], sA[tid]);
}

// ---------------- Kernel C: fused BN-fold + final FC + relu, transposed write (R3-proven) -----
__global__ __launch_bounds__(256) void out_kernel(
    const float* __restrict__ attnbuf, const float* __restrict__ statsA,
    const float* __restrict__ Wo, const float* __restrict__ bo,
    const float* __restrict__ go, const float* __restrict__ betao,
    float* __restrict__ outp)
{
    __shared__ float effWo[16][8];  // [d][i]
    __shared__ float effbo[16];

    int tid = threadIdx.x;
    if (tid < 16) {
        int d = tid;
        float mA[8];
#pragma unroll
        for (int i = 0; i < 8; ++i) mA[i] = statsA[i] * INV_NPOS;
        float mean = bo[d];
#pragma unroll
        for (int i = 0; i < 8; ++i) mean = fmaf(mA[i], Wo[i * 16 + d], mean);
        float var = 0.f;
        int cnt = 0;
#pragma unroll
        for (int i = 0; i < 8; ++i) {
#pragma unroll
            for (int j = i; j < 8; ++j) {
                float cov = statsA[8 + cnt] * INV_NPOS - mA[i] * mA[j];
                ++cnt;
                float wterm = Wo[i * 16 + d] * Wo[j * 16 + d];
                var += (i == j) ? wterm * cov : 2.f * wterm * cov;
            }
        }
        float s = go[d] * rsqrtf(var + BN_EPS);
        for (int i = 0; i < 8; ++i) effWo[d][i] = Wo[i * 16 + d] * s;
        effbo[d] = bo[d] * s + betao[d] - mean * s;
    }
    __syncthreads();

    int w = tid >> 6, lane = tid & 63;
    int pair = blockIdx.x * 4 + w;
    int b = pair >> 9, n = pair & 511;

    const float4* src = (const float4*)(attnbuf + (size_t)pair * 512 + lane * 8);
    float4 a0 = src[0], a1 = src[1];
    float a[8] = { a0.x, a0.y, a0.z, a0.w, a1.x, a1.y, a1.z, a1.w };

    float* ob = outp + b * B_STRIDE + n * 64 + lane;
#pragma unroll
    for (int d = 0; d < 16; ++d) {
        const float4* wr = (const float4*)(&effWo[d][0]);
        float4 w0 = wr[0], w1 = wr[1];
        float o = effbo[d];
        o = fmaf(a[0], w0.x, fmaf(a[1], w0.y, fmaf(a[2], w0.z, fmaf(a[3], w0.w, o))));
        o = fmaf(a[4], w1.x, fmaf(a[5], w1.y, fmaf(a[6], w1.z, fmaf(a[7], w1.w, o))));
        ob[d * CH_STRIDE] = fmaxf(o, 0.f);
    }
}

extern "C" void kernel_launch(void* const* d_in, const int* in_sizes, int n_in,
                              void* d_out, int out_size, void* d_ws, size_t ws_size,
                              hipStream_t stream)
{
    const float* x     = (const float*)d_in[0];
    const float* Wq    = (const float*)d_in[2];
    const float* bq    = (const float*)d_in[3];
    const float* gq    = (const float*)d_in[4];
    const float* betaq = (const float*)d_in[5];
    const float* Wk    = (const float*)d_in[6];
    const float* bk    = (const float*)d_in[7];
    const float* gk    = (const float*)d_in[8];
    const float* betak = (const float*)d_in[9];
    const float* Wv    = (const float*)d_in[10];
    const float* bv    = (const float*)d_in[11];
    const float* gv    = (const float*)d_in[12];
    const float* betav = (const float*)d_in[13];
    const float* Wo    = (const float*)d_in[14];
    const float* bo    = (const float*)d_in[15];
    const float* go    = (const float*)d_in[16];
    const float* betao = (const float*)d_in[17];

    float* ws      = (float*)d_ws;
    float* stats   = ws;          // 48
    float* statsA  = ws + 48;     // 44
    float* attnbuf = ws + 1024;   // 16 MiB

    hipMemsetAsync(d_ws, 0, 512, stream);

    stats_qkv_kernel<<<512, 256, 0, stream>>>(x, Wq, bq, Wk, bk, Wv, bv, stats);
    attn_kernel<<<2048, 256, 0, stream>>>(x, stats,
                                          Wq, bq, gq, betaq,
                                          Wk, bk, gk, betak,
                                          Wv, bv, gv, betav,
                                          attnbuf, statsA);
    out_kernel<<<2048, 256, 0, stream>>>(attnbuf, statsA, Wo, bo, go, betao, (float*)d_out);
}

// Round 11
// 205.424 us; speedup vs baseline: 1.0572x; 1.0572x over previous
//
#include <hip/hip_runtime.h>
#include <math.h>

// x [B=16, Cin=16, N=512, T=64], D=8, heads H=4, head_dim K=2
#define NPOS      524288   // B*T*N
#define CH_STRIDE 32768    // N*T
#define B_STRIDE  524288   // Cin*N*T
#define BN_EPS    1e-5f
#define INV_NPOS  (1.0f / 524288.0f)
#define LOG2E     1.44269504088896340736f

__device__ __forceinline__ float wave_red64(float v) {
    v += __shfl_xor(v, 32);
    v += __shfl_xor(v, 16);
    v += __shfl_xor(v, 8);
    v += __shfl_xor(v, 4);
    v += __shfl_xor(v, 2);
    v += __shfl_xor(v, 1);
    return v;
}

__device__ __forceinline__ float exp2_fast(float x) {
#if __has_builtin(__builtin_amdgcn_exp2f)
    return __builtin_amdgcn_exp2f(x);
#else
    float r;
    asm volatile("v_exp_f32 %0, %1\n\ts_nop 1" : "=v"(r) : "v"(x));
    return r;
#endif
}

__device__ __forceinline__ float rlane(float v, int lane) {
    return __int_as_float(__builtin_amdgcn_readlane(__float_as_int(v), lane));
}

// Wave-64 sum via DPP (VALU pipe only — no ds_swizzle): row_shr 1/2/4/8 builds
// per-16-row inclusive scans; row_bcast15 (rows 1,3) then row_bcast31 (rows 2,3)
// merge rows. Full sum lands in lane 63. Classic gfx9/CDNA reduction ladder.
__device__ __forceinline__ float dpp_red_lane63(float x) {
    int v;
    v = __builtin_amdgcn_update_dpp(0, __float_as_int(x), 0x111, 0xf, 0xf, true); x += __int_as_float(v);
    v = __builtin_amdgcn_update_dpp(0, __float_as_int(x), 0x112, 0xf, 0xf, true); x += __int_as_float(v);
    v = __builtin_amdgcn_update_dpp(0, __float_as_int(x), 0x114, 0xf, 0xf, true); x += __int_as_float(v);
    v = __builtin_amdgcn_update_dpp(0, __float_as_int(x), 0x118, 0xf, 0xf, true); x += __int_as_float(v);
    v = __builtin_amdgcn_update_dpp(0, __float_as_int(x), 0x142, 0xa, 0xf, true); x += __int_as_float(v); // bcast15 -> rows 1,3
    v = __builtin_amdgcn_update_dpp(0, __float_as_int(x), 0x143, 0xc, 0xf, true); x += __int_as_float(v); // bcast31 -> rows 2,3
    return x;
}

// ---------------- Kernel A: per-channel sum/sumsq of y = x@W + b for q,k,v ----------------
// 512 blocks x 256 thr; each thread: 4 consecutive positions via float4 loads. (R3-proven)
__global__ __launch_bounds__(256) void stats_qkv_kernel(
    const float* __restrict__ x,
    const float* __restrict__ Wq, const float* __restrict__ bq,
    const float* __restrict__ Wk, const float* __restrict__ bk,
    const float* __restrict__ Wv, const float* __restrict__ bv,
    float* __restrict__ stats /* [48]: sum[24], sumsq[24] */)
{
    float acc_s[24], acc_q[24];
#pragma unroll
    for (int j = 0; j < 24; ++j) { acc_s[j] = 0.f; acc_q[j] = 0.f; }

    int t = blockIdx.x * 256 + threadIdx.x;   // 131072 threads
    int p = t * 4;
    int b = p >> 15;
    int r = p & 32767;
    const float* xb = x + b * B_STRIDE + r;

    float4 xv[16];
#pragma unroll
    for (int c = 0; c < 16; ++c) xv[c] = *(const float4*)(xb + c * CH_STRIDE);

#pragma unroll
    for (int j = 0; j < 8; ++j) {
        float4 yq = make_float4(bq[j], bq[j], bq[j], bq[j]);
        float4 yk = make_float4(bk[j], bk[j], bk[j], bk[j]);
        float4 yv = make_float4(bv[j], bv[j], bv[j], bv[j]);
#pragma unroll
        for (int c = 0; c < 16; ++c) {
            float wq = Wq[c * 8 + j], wk = Wk[c * 8 + j], wv = Wv[c * 8 + j];
            yq.x = fmaf(xv[c].x, wq, yq.x); yq.y = fmaf(xv[c].y, wq, yq.y);
            yq.z = fmaf(xv[c].z, wq, yq.z); yq.w = fmaf(xv[c].w, wq, yq.w);
            yk.x = fmaf(xv[c].x, wk, yk.x); yk.y = fmaf(xv[c].y, wk, yk.y);
            yk.z = fmaf(xv[c].z, wk, yk.z); yk.w = fmaf(xv[c].w, wk, yk.w);
            yv.x = fmaf(xv[c].x, wv, yv.x); yv.y = fmaf(xv[c].y, wv, yv.y);
            yv.z = fmaf(xv[c].z, wv, yv.z); yv.w = fmaf(xv[c].w, wv, yv.w);
        }
        acc_s[j]      += (yq.x + yq.y) + (yq.z + yq.w);
        acc_q[j]      += fmaf(yq.x, yq.x, yq.y * yq.y) + fmaf(yq.z, yq.z, yq.w * yq.w);
        acc_s[8 + j]  += (yk.x + yk.y) + (yk.z + yk.w);
        acc_q[8 + j]  += fmaf(yk.x, yk.x, yk.y * yk.y) + fmaf(yk.z, yk.z, yk.w * yk.w);
        acc_s[16 + j] += (yv.x + yv.y) + (yv.z + yv.w);
        acc_q[16 + j] += fmaf(yv.x, yv.x, yv.y * yv.y) + fmaf(yv.z, yv.z, yv.w * yv.w);
    }

    __shared__ float red[4][48];
    int w = threadIdx.x >> 6, lane = threadIdx.x & 63;
#pragma unroll
    for (int j = 0; j < 24; ++j) {
        float vs = wave_red64(acc_s[j]);
        float vq = wave_red64(acc_q[j]);
        if (lane == 0) { red[w][j] = vs; red[w][24 + j] = vq; }
    }
    __syncthreads();
    if (threadIdx.x < 48) {
        float v = red[0][threadIdx.x] + red[1][threadIdx.x] + red[2][threadIdx.x] + red[3][threadIdx.x];
        atomicAdd(&stats[threadIdx.x], v);
    }
}

// ---------------- Kernel B: fused BN-fold + qkv + attention + DPP statsA epilogue ------------
// One wave per (b,n) pair. lane = t. k/v broadcast via v_readlane (VALU; measured 62.7 vs
// 82 us for LDS broadcast). statsA reduction via DPP ladder (VALU) instead of shfl_xor
// (ds_swizzle, DS pipe) — the shfl epilogue measured ~20 us of DS-pipe serialization.
__global__ __launch_bounds__(256) void attn_kernel(
    const float* __restrict__ x, const float* __restrict__ stats,
    const float* __restrict__ Wq, const float* __restrict__ bq,
    const float* __restrict__ gq, const float* __restrict__ betaq,
    const float* __restrict__ Wk, const float* __restrict__ bk,
    const float* __restrict__ gk, const float* __restrict__ betak,
    const float* __restrict__ Wv, const float* __restrict__ bv,
    const float* __restrict__ gv, const float* __restrict__ betav,
    float* __restrict__ attnbuf /* [8192][64][8] */,
    float* __restrict__ statsA  /* [44]: sum[8], cross[36] */)
{
    __shared__ float effW[24][16];       // [out j][in c]
    __shared__ float effB[24];
    __shared__ float sAw[4][44];         // per-wave partial stats

    int tid = threadIdx.x;
    if (tid < 24) {
        int grp = tid >> 3, jj = tid & 7;
        const float* W  = (grp == 0) ? Wq : (grp == 1) ? Wk : Wv;
        const float* bb = (grp == 0) ? bq : (grp == 1) ? bk : bv;
        const float* g  = (grp == 0) ? gq : (grp == 1) ? gk : gv;
        const float* be = (grp == 0) ? betaq : (grp == 1) ? betak : betav;
        float mean = stats[tid] * INV_NPOS;
        float var  = stats[24 + tid] * INV_NPOS - mean * mean;
        float s    = g[jj] * rsqrtf(var + BN_EPS);
        float a    = (grp == 0) ? 0.5f * LOG2E : 1.0f;  // fold 1/sqrt(d) + log2e into q (relu(y)*a==relu(y*a), a>0)
        float sa   = s * a;
        for (int c = 0; c < 16; ++c) effW[tid][c] = W[c * 8 + jj] * sa;
        effB[tid] = (bb[jj] * s + be[jj] - mean * s) * a;
    }
    __syncthreads();

    int w = tid >> 6, lane = tid & 63;
    int pair = blockIdx.x * 4 + w;     // grid 2048 -> 8192 pairs
    int b = pair >> 9, n = pair & 511;
    const float* xb = x + b * B_STRIDE + n * 64 + lane;

    float xv[16];
#pragma unroll
    for (int c = 0; c < 16; ++c) xv[c] = xb[c * CH_STRIDE];

    float q[8], kk[8], vv[8];
#pragma unroll
    for (int jj = 0; jj < 8; ++jj) {
        float yq = effB[jj], yk = effB[8 + jj], yv = effB[16 + jj];
        const float4* wq4 = (const float4*)(&effW[jj][0]);
        const float4* wk4 = (const float4*)(&effW[8 + jj][0]);
        const float4* wv4 = (const float4*)(&effW[16 + jj][0]);
#pragma unroll
        for (int c4 = 0; c4 < 4; ++c4) {
            float4 a4 = wq4[c4], b4 = wk4[c4], c4v = wv4[c4];
            yq = fmaf(xv[4*c4+0], a4.x, fmaf(xv[4*c4+1], a4.y, fmaf(xv[4*c4+2], a4.z, fmaf(xv[4*c4+3], a4.w, yq))));
            yk = fmaf(xv[4*c4+0], b4.x, fmaf(xv[4*c4+1], b4.y, fmaf(xv[4*c4+2], b4.z, fmaf(xv[4*c4+3], b4.w, yk))));
            yv = fmaf(xv[4*c4+0], c4v.x, fmaf(xv[4*c4+1], c4v.y, fmaf(xv[4*c4+2], c4v.z, fmaf(xv[4*c4+3], c4v.w, yv))));
        }
        q[jj]  = fmaxf(yq, 0.f);
        kk[jj] = fmaxf(yk, 0.f);
        vv[jj] = fmaxf(yv, 0.f);
    }

    float se[4], o0[4], o1[4];
#pragma unroll
    for (int h = 0; h < 4; ++h) { se[h] = 0.f; o0[h] = 0.f; o1[h] = 0.f; }

#pragma unroll 8
    for (int j = 0; j < 64; ++j) {
#pragma unroll
        for (int h = 0; h < 4; ++h) {
            float k0 = rlane(kk[2*h],     j);
            float k1 = rlane(kk[2*h + 1], j);
            float v0 = rlane(vv[2*h],     j);
            float v1 = rlane(vv[2*h + 1], j);
            float e = exp2_fast(fmaf(q[2*h], k0, q[2*h + 1] * k1));
            se[h] += e;
            o0[h] = fmaf(e, v0, o0[h]);
            o1[h] = fmaf(e, v1, o1[h]);
        }
    }

    float out[8];
#pragma unroll
    for (int h = 0; h < 4; ++h) {
        float inv = 1.0f / se[h];
        out[2*h]     = o0[h] * inv;
        out[2*h + 1] = o1[h] * inv;
    }

    float4* dst = (float4*)(attnbuf + (size_t)pair * 512 + lane * 8);
    dst[0] = make_float4(out[0], out[1], out[2], out[3]);
    dst[1] = make_float4(out[4], out[5], out[6], out[7]);

    // statsA epilogue: DPP reductions (VALU pipe), lane 63 stores per-wave partials.
#pragma unroll
    for (int i = 0; i < 8; ++i) {
        float t = dpp_red_lane63(out[i]);
        if (lane == 63) sAw[w][i] = t;
    }
    {
        int cnt = 8;
#pragma unroll
        for (int i = 0; i < 8; ++i) {
#pragma unroll
            for (int j2 = i; j2 < 8; ++j2) {
                float t = dpp_red_lane63(out[i] * out[j2]);
                if (lane == 63) sAw[w][cnt] = t;
                ++cnt;
            }
        }
    }
    __syncthreads();
    if (tid < 44) {
        float v = sAw[0][tid] + sAw[1][tid] + sAw[2][tid] + sAw[3][tid];
        atomicAdd(&statsA[tid], v);
    }
}

// ---------------- Kernel C: fused BN-fold + final FC + relu, transposed write (R3-proven) -----
__global__ __launch_bounds__(256) void out_kernel(
    const float* __restrict__ attnbuf, const float* __restrict__ statsA,
    const float* __restrict__ Wo, const float* __restrict__ bo,
    const float* __restrict__ go, const float* __restrict__ betao,
    float* __restrict__ outp)
{
    __shared__ float effWo[16][8];  // [d][i]
    __shared__ float effbo[16];

    int tid = threadIdx.x;
    if (tid < 16) {
        int d = tid;
        float mA[8];
#pragma unroll
        for (int i = 0; i < 8; ++i) mA[i] = statsA[i] * INV_NPOS;
        float mean = bo[d];
#pragma unroll
        for (int i = 0; i < 8; ++i) mean = fmaf(mA[i], Wo[i * 16 + d], mean);
        float var = 0.f;
        int cnt = 0;
#pragma unroll
        for (int i = 0; i < 8; ++i) {
#pragma unroll
            for (int j = i; j < 8; ++j) {
                float cov = statsA[8 + cnt] * INV_NPOS - mA[i] * mA[j];
                ++cnt;
                float wterm = Wo[i * 16 + d] * Wo[j * 16 + d];
                var += (i == j) ? wterm * cov : 2.f * wterm * cov;
            }
        }
        float s = go[d] * rsqrtf(var + BN_EPS);
        for (int i = 0; i < 8; ++i) effWo[d][i] = Wo[i * 16 + d] * s;
        effbo[d] = bo[d] * s + betao[d] - mean * s;
    }
    __syncthreads();

    int w = tid >> 6, lane = tid & 63;
    int pair = blockIdx.x * 4 + w;
    int b = pair >> 9, n = pair & 511;

    const float4* src = (const float4*)(attnbuf + (size_t)pair * 512 + lane * 8);
    float4 a0 = src[0], a1 = src[1];
    float a[8] = { a0.x, a0.y, a0.z, a0.w, a1.x, a1.y, a1.z, a1.w };

    float* ob = outp + b * B_STRIDE + n * 64 + lane;
#pragma unroll
    for (int d = 0; d < 16; ++d) {
        const float4* wr = (const float4*)(&effWo[d][0]);
        float4 w0 = wr[0], w1 = wr[1];
        float o = effbo[d];
        o = fmaf(a[0], w0.x, fmaf(a[1], w0.y, fmaf(a[2], w0.z, fmaf(a[3], w0.w, o))));
        o = fmaf(a[4], w1.x, fmaf(a[5], w1.y, fmaf(a[6], w1.z, fmaf(a[7], w1.w, o))));
        ob[d * CH_STRIDE] = fmaxf(o, 0.f);
    }
}

extern "C" void kernel_launch(void* const* d_in, const int* in_sizes, int n_in,
                              void* d_out, int out_size, void* d_ws, size_t ws_size,
                              hipStream_t stream)
{
    const float* x     = (const float*)d_in[0];
    const float* Wq    = (const float*)d_in[2];
    const float* bq    = (const float*)d_in[3];
    const float* gq    = (const float*)d_in[4];
    const float* betaq = (const float*)d_in[5];
    const float* Wk    = (const float*)d_in[6];
    const float* bk    = (const float*)d_in[7];
    const float* gk    = (const float*)d_in[8];
    const float* betak = (const float*)d_in[9];
    const float* Wv    = (const float*)d_in[10];
    const float* bv    = (const float*)d_in[11];
    const float* gv    = (const float*)d_in[12];
    const float* betav = (const float*)d_in[13];
    const float* Wo    = (const float*)d_in[14];
    const float* bo    = (const float*)d_in[15];
    const float* go    = (const float*)d_in[16];
    const float* betao = (const float*)d_in[17];

    float* ws      = (float*)d_ws;
    float* stats   = ws;          // 48
    float* statsA  = ws + 48;     // 44
    float* attnbuf = ws + 1024;   // 16 MiB

    hipMemsetAsync(d_ws, 0, 512, stream);

    stats_qkv_kernel<<<512, 256, 0, stream>>>(x, Wq, bq, Wk, bk, Wv, bv, stats);
    attn_kernel<<<2048, 256, 0, stream>>>(x, stats,
                                          Wq, bq, gq, betaq,
                                          Wk, bk, gk, betak,
                                          Wv, bv, gv, betav,
                                          attnbuf, statsA);
    out_kernel<<<2048, 256, 0, stream>>>(attnbuf, statsA, Wo, bo, go, betao, (float*)d_out);
}